// Round 13
// baseline (22.903 us; speedup 1.0000x reference)
//
#include <hip/hip_runtime.h>
#include <hip/hip_bf16.h>

typedef unsigned short ushort_t;
typedef unsigned int uint_t;
typedef __attribute__((ext_vector_type(8))) short short8;
typedef __attribute__((ext_vector_type(4))) float f32x4;

#define IN_DIM 256
#define OUT_DIM 256
#define NSPL 11                  // 11 bases
#define KSLOT 12                 // + silu/residual slot
#define CHUNK_I 16               // inputs per K-chunk
#define KC (CHUNK_I * KSLOT)     // 192 K-slots per chunk
#define LSTRIDE (KC + 8)         // 200 ushorts = 400B row stride; slots KC..KC+7 = pad/dump
#define NCHUNK 8                 // chunks per K-half (this block's share)
#define RAWF 180                 // raw f32 coef row: 176 floats + 4 pad

__device__ __forceinline__ uint_t pk2(float lo, float hi) {
  __hip_bfloat162 h = __float22bfloat162_rn(make_float2(lo, hi));  // v_cvt_pk_bf16_f32, RNE
  union { __hip_bfloat162 h2; uint_t u; } c; c.h2 = h;
  return c.u;
}

// A-cell: closed-form cubic B-spline; placement via LDS scatter (address path).
// OOB slots redirect to the row's pad region (never read by MFMA).
__device__ __forceinline__ void packA_scatter(ushort_t* cb, ushort_t* dump, float xf) {
  const float t = (xf + 1.75f) * 4.0f;
  const float fJ = floorf(t);
  const int J = (int)fJ;
  const float u = t - fJ;
  const float u2 = u * u, u3 = u2 * u, um = 1.0f - u;
  const float n0 = um * um * um * (1.0f / 6.0f);                        // slot J-3
  const float n1 = 0.5f * u3 - u2 + (4.0f / 6.0f);                      // slot J-2
  const float n2 = -0.5f * u3 + 0.5f * u2 + 0.5f * u + (1.0f / 6.0f);   // slot J-1
  const float n3 = u3 * (1.0f / 6.0f);                                  // slot J
  const float silu = xf / (1.0f + __expf(-xf));

  // zero the 12-slot cell (compiler merges to wide ds_writes)
#pragma unroll
  for (int z = 0; z < 12; ++z) cb[z] = 0;

  const uint_t p01 = pk2(n0, n1);
  const uint_t p23 = pk2(n2, n3);
  const uint_t psl = pk2(silu, silu);

  const int base = J - 3;
  ushort_t* w0 = ((unsigned)(base + 0) <= 10u) ? (cb + base + 0) : (dump + 0);
  ushort_t* w1 = ((unsigned)(base + 1) <= 10u) ? (cb + base + 1) : (dump + 1);
  ushort_t* w2 = ((unsigned)(base + 2) <= 10u) ? (cb + base + 2) : (dump + 2);
  ushort_t* w3 = ((unsigned)(base + 3) <= 10u) ? (cb + base + 3) : (dump + 3);
  *w0 = (ushort_t)p01;
  *w1 = (ushort_t)(p01 >> 16);
  *w2 = (ushort_t)p23;
  *w3 = (ushort_t)(p23 >> 16);
  cb[11] = (ushort_t)psl;
}

// W-cell from f32 LDS row: 11 contiguous floats * us, + r slot -> 6 packed dwords
__device__ __forceinline__ void packW_f32(const float* c, float us, float r, uint_t o6[6]) {
  o6[0] = pk2(us * c[0], us * c[1]);
  o6[1] = pk2(us * c[2], us * c[3]);
  o6[2] = pk2(us * c[4], us * c[5]);
  o6[3] = pk2(us * c[6], us * c[7]);
  o6[4] = pk2(us * c[8], us * c[9]);
  o6[5] = pk2(us * c[10], r);
}

__device__ __forceinline__ void writeT(ushort_t* dst, const uint_t* p) {
  uint_t* d = (uint_t*)dst;
#pragma unroll
  for (int j = 0; j < 6; ++j) d[j] = p[j];
}

// 1024 blocks x 256 threads; block = (tile T, K-half s). Per chunk (16 inputs):
// coalesced scalar coef loads -> f32 rawc LDS (wave-local, no barrier) ->
// pack A (LDS scatter) / W (mul+pk2) into double-buffered tiles; wave-pairs
// alternate chunks for MFMA (96 K each). Partial sums atomically added to out
// (zeroed by a memset node each call).
__global__ __launch_bounds__(256, 4) void fused(const float* __restrict__ x,
                                                const float* __restrict__ coef,
                                                const float* __restrict__ rw,
                                                const float* __restrict__ uw,
                                                float* __restrict__ out) {
  __shared__ __attribute__((aligned(16))) ushort_t As[2][16 * LSTRIDE];
  __shared__ __attribute__((aligned(16))) ushort_t Ws[2][16 * LSTRIDE];
  __shared__ __attribute__((aligned(16))) float rawc[16][RAWF];   // reused as `red` at end

  const int tid = threadIdx.x;
  const int lane = tid & 63;
  const int w = tid >> 6;                          // wave 0..3
  const int B = blockIdx.x;
  const int T = B >> 1;                            // tile 0..511
  const int s = B & 1;                             // K-half
  const int mt = T >> 4;                           // 0..31
  const int nt = ((T & 7) << 1) | ((T >> 3) & 1);  // 0..15 (bijective)
  const int b0 = mt * 16, o0 = nt * 16;
  const int kb0 = s * 128;                         // input-index base of this K-half
  const int mn = lane & 15;
  const int klane = (lane >> 4) * 8;

  const int row = tid >> 4;                        // 0..15: tile row this thread builds
  const int i0 = tid & 15;                         // input within chunk

  // staged registers for one chunk (one A-cell + one W-cell per thread)
  float cfs[11];
  float xa, us, rr;

#define LOADC(C)                                                              \
  {                                                                           \
    const int ib = kb0 + (C) * CHUNK_I;                                       \
    xa = x[(b0 + row) * IN_DIM + ib + i0];                                    \
    const int orow = o0 + row;                                                \
    us = uw[orow * IN_DIM + ib + i0];                                         \
    rr = rw[orow * IN_DIM + ib + i0];                                         \
    const float* csrc = coef + ((size_t)orow * IN_DIM + ib) * NSPL;           \
    _Pragma("unroll")                                                         \
    for (int j = 0; j < 11; ++j) cfs[j] = csrc[i0 + j * 16];  /* 64B/16 lanes */ \
  }

  // raw f32 store; same-wave consumer (same row group) -> no barrier needed
#define CVTSTORE                                                              \
  {                                                                           \
    _Pragma("unroll")                                                         \
    for (int j = 0; j < 11; ++j) rawc[row][i0 + j * 16] = cfs[j];             \
  }

#define PACK(BUF)                                                             \
  {                                                                           \
    ushort_t* arow = &As[BUF][row * LSTRIDE];                                 \
    packA_scatter(arow + i0 * KSLOT, arow + KC, xa);                          \
    uint_t p6[6];                                                             \
    packW_f32(&rawc[row][NSPL * i0], us, rr, p6);                             \
    writeT(&Ws[BUF][row * LSTRIDE + i0 * KSLOT], p6);                         \
  }

  f32x4 acc = {0.f, 0.f, 0.f, 0.f};

  // prologue: chunk 0 (CVTSTORE->PACK is wave-local, no barrier between)
  LOADC(0)
  CVTSTORE
  PACK(0)
  __syncthreads();

  for (int c = 0; c < NCHUNK; ++c) {
    const int cur = c & 1;

    if (c + 1 < NCHUNK) { LOADC(c + 1) }       // issue next chunk's (coalesced) loads
    __builtin_amdgcn_sched_barrier(0);         // keep them issued before MFMA

    // MFMA: wave-pair (w>>1) handles chunks of matching parity; 96 K per wave
    if ((w >> 1) == (c & 1)) {
      __builtin_amdgcn_s_setprio(1);
      const int kb = (w & 1) * 96;
#pragma unroll
      for (int q = 0; q < 3; ++q) {
        const int k = kb + q * 32 + klane;
        short8 af  = *(const short8*)&As[cur][mn * LSTRIDE + k];
        short8 bfr = *(const short8*)&Ws[cur][mn * LSTRIDE + k];
        acc = __builtin_amdgcn_mfma_f32_16x16x32_bf16(af, bfr, acc, 0, 0, 0);
      }
      __builtin_amdgcn_s_setprio(0);
    }

    if (c + 1 < NCHUNK) {
      CVTSTORE                                 // waits vmcnt; wave-local rawc
      PACK(cur ^ 1)                            // build next chunk into other buffer
    }
    __syncthreads();                           // ONE barrier per chunk
  }

  // cross-wave reduce (red overlays the now-dead rawc), then atomic-add to out
  f32x4* red = (f32x4*)&rawc[0][0];
  if (w > 0) red[(w - 1) * 64 + lane] = acc;
  __syncthreads();

  if (w == 0) {
    const f32x4 q0 = red[lane];
    const f32x4 q1 = red[64 + lane];
    const f32x4 q2 = red[128 + lane];
#pragma unroll
    for (int q = 0; q < 4; ++q) acc[q] += q0[q] + q1[q] + q2[q];

    // C/D layout (HW-verified): col = lane&15, row = (lane>>4)*4 + reg
    const int col = o0 + mn;
    const int rbase = b0 + (lane >> 4) * 4;
#pragma unroll
    for (int r = 0; r < 4; ++r) {
      __hip_atomic_fetch_add(&out[(size_t)(rbase + r) * OUT_DIM + col], acc[r],
                             __ATOMIC_RELAXED, __HIP_MEMORY_SCOPE_AGENT);
    }
  }
}

extern "C" void kernel_launch(void* const* d_in, const int* in_sizes, int n_in,
                              void* d_out, int out_size, void* d_ws, size_t ws_size,
                              hipStream_t stream) {
  const float* x    = (const float*)d_in[0];
  const float* coef = (const float*)d_in[1];
  const float* rw   = (const float*)d_in[2];
  const float* uw   = (const float*)d_in[3];
  float* out = (float*)d_out;

  hipMemsetAsync(out, 0, (size_t)out_size * sizeof(float), stream);  // split-K accumulator base
  fused<<<1024, 256, 0, stream>>>(x, coef, rw, uw, out);
}

// Round 14
// 18.674 us; speedup vs baseline: 1.2264x; 1.2264x over previous
//
#include <hip/hip_runtime.h>
#include <hip/hip_bf16.h>

typedef unsigned short ushort_t;
typedef unsigned int uint_t;
typedef __attribute__((ext_vector_type(8))) short short8;
typedef __attribute__((ext_vector_type(4))) float f32x4;

#define IN_DIM 256
#define OUT_DIM 256
#define NSPL 11                  // 11 bases
#define KSLOT 12                 // + silu/residual slot
#define CHUNK_I 32               // inputs per K-chunk
#define KC (CHUNK_I * KSLOT)     // 384 K-slots per chunk
#define LSTRIDE (KC + 8)         // 392 ushorts = 784B row stride; slots KC..KC+7 = pad/dump
#define NCHUNK 8
#define RAWF 356                 // raw f32 coef row: 352 floats (176 float2) + 4 pad

__device__ __forceinline__ uint_t pk2(float lo, float hi) {
  __hip_bfloat162 h = __float22bfloat162_rn(make_float2(lo, hi));  // v_cvt_pk_bf16_f32, RNE
  union { __hip_bfloat162 h2; uint_t u; } c; c.h2 = h;
  return c.u;
}

// A-cell: closed-form cubic B-spline; placement via LDS scatter (address path).
// OOB slots redirect to the row's pad region (never read by MFMA).
__device__ __forceinline__ void packA_scatter(ushort_t* cb, ushort_t* dump, float xf) {
  const float t = (xf + 1.75f) * 4.0f;
  const float fJ = floorf(t);
  const int J = (int)fJ;
  const float u = t - fJ;
  const float u2 = u * u, u3 = u2 * u, um = 1.0f - u;
  const float n0 = um * um * um * (1.0f / 6.0f);                        // slot J-3
  const float n1 = 0.5f * u3 - u2 + (4.0f / 6.0f);                      // slot J-2
  const float n2 = -0.5f * u3 + 0.5f * u2 + 0.5f * u + (1.0f / 6.0f);   // slot J-1
  const float n3 = u3 * (1.0f / 6.0f);                                  // slot J
  const float silu = xf / (1.0f + __expf(-xf));

  // zero the 12-slot cell (compiler merges to wide ds_writes)
#pragma unroll
  for (int z = 0; z < 12; ++z) cb[z] = 0;

  const uint_t p01 = pk2(n0, n1);
  const uint_t p23 = pk2(n2, n3);
  const uint_t psl = pk2(silu, silu);

  const int base = J - 3;
  ushort_t* w0 = ((unsigned)(base + 0) <= 10u) ? (cb + base + 0) : (dump + 0);
  ushort_t* w1 = ((unsigned)(base + 1) <= 10u) ? (cb + base + 1) : (dump + 1);
  ushort_t* w2 = ((unsigned)(base + 2) <= 10u) ? (cb + base + 2) : (dump + 2);
  ushort_t* w3 = ((unsigned)(base + 3) <= 10u) ? (cb + base + 3) : (dump + 3);
  *w0 = (ushort_t)p01;
  *w1 = (ushort_t)(p01 >> 16);
  *w2 = (ushort_t)p23;
  *w3 = (ushort_t)(p23 >> 16);
  cb[11] = (ushort_t)psl;
}

// W-cell from f32 LDS row: 11 contiguous floats * us, + r slot -> 6 packed dwords
__device__ __forceinline__ void packW_f32(const float* c, float us, float r, uint_t o6[6]) {
  o6[0] = pk2(us * c[0], us * c[1]);
  o6[1] = pk2(us * c[2], us * c[3]);
  o6[2] = pk2(us * c[4], us * c[5]);
  o6[3] = pk2(us * c[6], us * c[7]);
  o6[4] = pk2(us * c[8], us * c[9]);
  o6[5] = pk2(us * c[10], r);
}

__device__ __forceinline__ void writeT(ushort_t* dst, const uint_t* p) {
  uint_t* d = (uint_t*)dst;
#pragma unroll
  for (int j = 0; j < 6; ++j) d[j] = p[j];
}

// ONE kernel, 512 blocks x 256 threads, zero cross-block sync.
// Unroll-by-2 chunk pipeline with TWO register stages (A=even chunks, B=odd):
// loads for chunk c+2 issue a full phase before their CVTSTORE consumes them,
// hiding L2 latency under the build+barrier+MFMA of the intervening chunk.
__global__ __launch_bounds__(256, 2) void fused(const float* __restrict__ x,
                                                const float* __restrict__ coef,
                                                const float* __restrict__ rw,
                                                const float* __restrict__ uw,
                                                float* __restrict__ out) {
  __shared__ __attribute__((aligned(16))) ushort_t As[2][16 * LSTRIDE];
  __shared__ __attribute__((aligned(16))) ushort_t Ws[2][16 * LSTRIDE];
  __shared__ __attribute__((aligned(16))) float rawc[16][RAWF];   // reused as `red` at end

  const int tid = threadIdx.x;
  const int lane = tid & 63;
  const int w = tid >> 6;                          // wave 0..3 = K-slice owner
  const int B = blockIdx.x;
  const int mt = B >> 4;                           // 0..31
  const int nt = ((B & 7) << 1) | ((B >> 3) & 1);  // XCD-aware: XCD r owns N-tiles {2r,2r+1}
  const int b0 = mt * 16, o0 = nt * 16;
  const int mn = lane & 15;
  const int klane = (lane >> 4) * 8;

  const int row = tid >> 4;                        // 0..15: tile row this thread builds (wave = row>>2)
  const int i0 = tid & 15;                         // cells (row,i0), (row,i0+16)

  // two independent register stages
  float2 cfA[11], cfB[11];
  float xaA0, xaA1, usA0, usA1, rrA0, rrA1;
  float xaB0, xaB1, usB0, usB1, rrB0, rrB1;

#define LOADC(S, C)                                                           \
  {                                                                           \
    const int ib = (C) * CHUNK_I;                                             \
    xa##S##0 = x[(b0 + row) * IN_DIM + ib + i0];                              \
    xa##S##1 = x[(b0 + row) * IN_DIM + ib + i0 + 16];                         \
    const int orow = o0 + row;                                                \
    us##S##0 = uw[orow * IN_DIM + ib + i0];                                   \
    us##S##1 = uw[orow * IN_DIM + ib + i0 + 16];                              \
    rr##S##0 = rw[orow * IN_DIM + ib + i0];                                   \
    rr##S##1 = rw[orow * IN_DIM + ib + i0 + 16];                              \
    const float2* csrc = (const float2*)(coef + ((size_t)orow * IN_DIM + ib) * NSPL); \
    _Pragma("unroll")                                                         \
    for (int j = 0; j < 11; ++j) cf##S[j] = csrc[i0 + j * 16];  /* 128B/16 lanes */ \
  }

  // raw f32 store + pack; rawc is wave-local (writer/reader same wave) -> no barrier
#define CVTPACK(S, BUF)                                                       \
  {                                                                           \
    float2* rrow = (float2*)&rawc[row][0];                                    \
    _Pragma("unroll")                                                         \
    for (int j = 0; j < 11; ++j) rrow[i0 + j * 16] = cf##S[j];                \
    ushort_t* arow = &As[BUF][row * LSTRIDE];                                 \
    packA_scatter(arow + i0 * KSLOT, arow + KC, xa##S##0);                    \
    packA_scatter(arow + (i0 + 16) * KSLOT, arow + KC, xa##S##1);             \
    uint_t p6[6];                                                             \
    packW_f32(&rawc[row][NSPL * i0], us##S##0, rr##S##0, p6);                 \
    writeT(&Ws[BUF][row * LSTRIDE + i0 * KSLOT], p6);                         \
    packW_f32(&rawc[row][NSPL * (i0 + 16)], us##S##1, rr##S##1, p6);          \
    writeT(&Ws[BUF][row * LSTRIDE + (i0 + 16) * KSLOT], p6);                  \
  }

#define MFMA3(BUF)                                                            \
  {                                                                           \
    _Pragma("unroll")                                                         \
    for (int q = 0; q < 3; ++q) {                                             \
      const int k = w * 96 + q * 32 + klane;                                  \
      short8 af  = *(const short8*)&As[BUF][mn * LSTRIDE + k];                \
      short8 bfr = *(const short8*)&Ws[BUF][mn * LSTRIDE + k];                \
      acc = __builtin_amdgcn_mfma_f32_16x16x32_bf16(af, bfr, acc, 0, 0, 0);   \
    }                                                                         \
  }

  f32x4 acc = {0.f, 0.f, 0.f, 0.f};

  // prologue: build chunk 0, put chunk 1 in flight
  LOADC(A, 0)
  CVTPACK(A, 0)
  LOADC(B, 1)
  __syncthreads();

#pragma unroll
  for (int cc = 0; cc < 4; ++cc) {
    // even chunk 2cc (buffer 0)
    MFMA3(0)
    if (cc < 3) { LOADC(A, 2 * cc + 2) }   // prefetch 2 ahead into freed A-stage
    CVTPACK(B, 1)                          // build odd chunk 2cc+1 (B loaded a full phase ago)
    __syncthreads();

    // odd chunk 2cc+1 (buffer 1)
    MFMA3(1)
    if (cc < 3) {
      LOADC(B, 2 * cc + 3)                 // prefetch 2 ahead into freed B-stage
      CVTPACK(A, 0)                        // build even chunk 2cc+2
    }
    __syncthreads();
  }

  // cross-wave split-K reduce (red overlays the now-dead rawc), then write
  f32x4* red = (f32x4*)&rawc[0][0];
  if (w > 0) red[(w - 1) * 64 + lane] = acc;
  __syncthreads();

  if (w == 0) {
    const f32x4 q0 = red[lane];
    const f32x4 q1 = red[64 + lane];
    const f32x4 q2 = red[128 + lane];
#pragma unroll
    for (int q = 0; q < 4; ++q) acc[q] += q0[q] + q1[q] + q2[q];

    // C/D layout (HW-verified): col = lane&15, row = (lane>>4)*4 + reg
    const int col = o0 + mn;
    const int rbase = b0 + (lane >> 4) * 4;
#pragma unroll
    for (int r = 0; r < 4; ++r) {
      out[(size_t)(rbase + r) * OUT_DIM + col] = acc[r];
    }
  }
}

extern "C" void kernel_launch(void* const* d_in, const int* in_sizes, int n_in,
                              void* d_out, int out_size, void* d_ws, size_t ws_size,
                              hipStream_t stream) {
  const float* x    = (const float*)d_in[0];
  const float* coef = (const float*)d_in[1];
  const float* rw   = (const float*)d_in[2];
  const float* uw   = (const float*)d_in[3];
  float* out = (float*)d_out;

  fused<<<512, 256, 0, stream>>>(x, coef, rw, uw, out);
}